// Round 1
// baseline (272.240 us; speedup 1.0000x reference)
//
#include <hip/hip_runtime.h>

// Problem constants (fixed by setup_inputs)
#define BQ   4
#define CQ   2
#define EQ   256
#define LQ   16000
#define WQ   40
#define STEP 20
#define TQ   ((LQ - 1) * STEP + WQ)   // 320020
#define TLF  63                       // owned-frame pitch per block (64 computed, 1 overlap)
#define OWN  (TLF * STEP)             // 1260 owned output samples per block
#define NBX  254                      // 254 * 1260 = 320040 >= 320020
#define NH   4                        // e-quarters
#define EH   (EQ / NH)                // 64 e's per thread
#define SPAN (TLF * STEP + WQ + STEP) // 1320 floats per (copy, c)
#define PF   8                        // K-loop prefetch depth (rows of e in flight)

// Pre-kernel: transpose basis [W][E] -> wsT [E][W] (fp32, rows contiguous)
// so the main loop can read each e-row with wave-uniform scalar loads.
__global__ void transpose_basis_kernel(const float* __restrict__ basis,
                                       float* __restrict__ wsT) {
    int i = blockIdx.x * 256 + threadIdx.x;
    if (i < EQ * WQ) {
        int e = i / WQ;
        int w = i - e * WQ;
        wsT[i] = basis[w * EQ + e];
    }
}

// One block: 512 threads = 4 e-quarters (h) x 2 channels (c) x 64 frames (ll).
// Thread (h,c,ll) computes partial frame f = 63*bx - 1 + ll over e-quarter h:
//   part[w] = sum_e mix[b,e,f]*mask[b,c,e,f]*wsT[e][w]   (wsT row in SGPRs).
// K-loop is software-pipelined PF=8 rows deep: 16 global loads stay in flight
// under each group's 320 FMAs (~1280 issue cycles) to cover HBM/L3 latency.
// Overlap-add into 2 LDS copies (one per h-pair), 4 serialized parity phases
// -> no atomics. Block stores the disjoint span t in [1260*bx, 1260*bx+1260).
__global__ __launch_bounds__(512, 5) void decoder_kernel(
    const float* __restrict__ mix,    // [B,E,L]
    const float* __restrict__ mask,   // [B,C,E,L]
    const float* __restrict__ wsT,    // [E,W] transposed basis
    float* __restrict__ out)          // [B,C,T]
{
    __shared__ float outS[2][CQ][SPAN];   // ~21 KB

    const int tid = threadIdx.x;
    const int ll  = tid & 63;                                  // frame lane
    const int c   = (tid >> 6) & 1;                            // channel (wave-uniform)
    const int h   = __builtin_amdgcn_readfirstlane(tid >> 7);  // e-quarter, forced uniform
    const int bx  = blockIdx.x;
    const int b   = blockIdx.y;
    const int f   = TLF * bx - 1 + ll;   // may be out of [0,LQ)

    // Clamp + validity multiplier: keeps the K-loop branch-free so the
    // wave-uniform basis loads can be scalarized (no divergent CF).
    const int   fc    = min(max(f, 0), LQ - 1);
    const float valid = (f >= 0 && f < LQ) ? 1.0f : 0.0f;

    float acc[WQ];
#pragma unroll
    for (int w = 0; w < WQ; ++w) acc[w] = 0.0f;

    const float* mp = mix  + ((size_t)b * EQ + h * EH) * LQ + fc;
    const float* kp = mask + (((size_t)(b * CQ + c)) * EQ + h * EH) * LQ + fc;
    const float* bp = wsT + (size_t)h * EH * WQ;   // wave-uniform

    // ---- software-pipelined K-loop: prefetch PF rows ahead ----
    float mb[PF], kb[PF];
#pragma unroll
    for (int j = 0; j < PF; ++j) {
        mb[j] = mp[(size_t)j * LQ];
        kb[j] = kp[(size_t)j * LQ];
    }

#pragma unroll 1
    for (int eo = 0; eo < EH - PF; eo += PF) {
        // issue next group's 16 loads first -> in flight under the FMAs
        float mn[PF], kn[PF];
#pragma unroll
        for (int j = 0; j < PF; ++j) {
            mn[j] = mp[(size_t)(eo + PF + j) * LQ];
            kn[j] = kp[(size_t)(eo + PF + j) * LQ];
        }
        // compute current group from registers (no memory wait here)
#pragma unroll
        for (int j = 0; j < PF; ++j) {
            const float s = mb[j] * kb[j] * valid;
            const float* bb = bp + (eo + j) * WQ;  // uniform -> s_load
#pragma unroll
            for (int w = 0; w < WQ; ++w) acc[w] = fmaf(s, bb[w], acc[w]);
        }
        // rotate (register-renamed by SSA; vmcnt wait lands before next use)
#pragma unroll
        for (int j = 0; j < PF; ++j) { mb[j] = mn[j]; kb[j] = kn[j]; }
    }
    // epilogue group (no prefetch)
    {
        const int eo = EH - PF;
#pragma unroll
        for (int j = 0; j < PF; ++j) {
            const float s = mb[j] * kb[j] * valid;
            const float* bb = bp + (eo + j) * WQ;
#pragma unroll
            for (int w = 0; w < WQ; ++w) acc[w] = fmaf(s, bb[w], acc[w]);
        }
    }

    // Overlap-add into LDS copy cp = h>>1. Within a copy, 4 serialized phases
    // (h-parity x ll-parity); even-ll ranges [20*ll,20*ll+40) tile [0,1280)
    // exactly, so phase 0 is a plain store (no pre-zero needed; indices
    // [1280,1300) are written by odd-ll adds but never read back).
    const int base = ll * STEP;
    const int cp   = h >> 1;
    const int hp   = h & 1;
    if (hp == 0 && (ll & 1) == 0) {
#pragma unroll
        for (int w = 0; w < WQ; ++w) outS[cp][c][base + w] = acc[w];
    }
    __syncthreads();
    if (hp == 0 && (ll & 1) == 1) {
#pragma unroll
        for (int w = 0; w < WQ; ++w) outS[cp][c][base + w] += acc[w];
    }
    __syncthreads();
    if (hp == 1 && (ll & 1) == 0) {
#pragma unroll
        for (int w = 0; w < WQ; ++w) outS[cp][c][base + w] += acc[w];
    }
    __syncthreads();
    if (hp == 1 && (ll & 1) == 1) {
#pragma unroll
        for (int w = 0; w < WQ; ++w) outS[cp][c][base + w] += acc[w];
    }
    __syncthreads();

    // Store owned span: t = 1260*bx + i  <->  outS[*][c][20 + i], i in [0,1260)
    for (int cc = 0; cc < CQ; ++cc) {
        const size_t ob = ((size_t)b * CQ + cc) * TQ + (size_t)OWN * bx;
        for (int i = tid; i < OWN; i += 512) {
            const long t = (long)OWN * bx + i;
            if (t < (long)TQ) {
                out[ob + i] = outS[0][cc][STEP + i] + outS[1][cc][STEP + i];
            }
        }
    }
}

extern "C" void kernel_launch(void* const* d_in, const int* in_sizes, int n_in,
                              void* d_out, int out_size, void* d_ws, size_t ws_size,
                              hipStream_t stream) {
    const float* mix   = (const float*)d_in[0];
    const float* mask  = (const float*)d_in[1];
    const float* basis = (const float*)d_in[2];
    float* out = (float*)d_out;
    float* wsT = (float*)d_ws;   // needs EQ*WQ*4 = 40960 bytes

    transpose_basis_kernel<<<dim3((EQ * WQ + 255) / 256), 256, 0, stream>>>(basis, wsT);

    dim3 grid(NBX, BQ);
    decoder_kernel<<<grid, 512, 0, stream>>>(mix, mask, wsT, out);
}

// Round 2
// 244.518 us; speedup vs baseline: 1.1134x; 1.1134x over previous
//
#include <hip/hip_runtime.h>

// Problem constants (fixed by setup_inputs)
#define BQ   4
#define CQ   2
#define EQ   256
#define LQ   16000
#define WQ   40
#define STEP 20
#define TQ   ((LQ - 1) * STEP + WQ)   // 320020
#define TLF  63                       // owned-frame pitch per block (64 computed, 1 overlap)
#define OWN  (TLF * STEP)             // 1260 owned output samples per block
#define NBX  254                      // 254 * 1260 = 320040 >= 320020
#define NH   8                        // e-octants (channels merged into each thread)
#define EH   (EQ / NH)                // 32 e's per thread
#define NCP  4                        // LDS accumulation copies (one per octant pair)
#define SPAN (TLF * STEP + WQ + STEP) // 1320 floats per (copy, c)

// Pre-kernel: transpose basis [W][E] -> wsT [E][W] (fp32, rows contiguous)
// so the main loop can read each e-row with wave-uniform scalar loads.
__global__ void transpose_basis_kernel(const float* __restrict__ basis,
                                       float* __restrict__ wsT) {
    int i = blockIdx.x * 256 + threadIdx.x;
    if (i < EQ * WQ) {
        int e = i / WQ;
        int w = i - e * WQ;
        wsT[i] = basis[w * EQ + e];
    }
}

// One block: 512 threads = 8 e-octants (h) x 64 frames (ll); BOTH channels per
// thread. Thread (h,ll) computes partial frame f = 63*bx - 1 + ll over
// e-octant h for c=0 and c=1:
//   accC[w] = sum_e mix[b,e,f]*mask[b,C,e,f]*wsT[e][w]   (wsT row in SGPRs).
// Channel-merge doubles FMAs per basis s_load word (2 v_fma share 1 SGPR
// operand), halving the scalar-stream stall per unit of work, and halves the
// mix load stream. Overlap-add into 4 LDS copies (one per octant pair), 4
// serialized parity phases -> no atomics. Block stores the disjoint span
// t in [1260*bx, 1260*bx+1260).
__global__ __launch_bounds__(512, 4) void decoder_kernel(
    const float* __restrict__ mix,    // [B,E,L]
    const float* __restrict__ mask,   // [B,C,E,L]
    const float* __restrict__ wsT,    // [E,W] transposed basis
    float* __restrict__ out)          // [B,C,T]
{
    __shared__ float outS[NCP][CQ][SPAN];   // ~42 KB

    const int tid = threadIdx.x;
    const int ll  = tid & 63;                                  // frame lane
    const int h   = __builtin_amdgcn_readfirstlane(tid >> 6);  // e-octant, forced uniform
    const int bx  = blockIdx.x;
    const int b   = blockIdx.y;
    const int f   = TLF * bx - 1 + ll;   // may be out of [0,LQ)

    // Clamp + validity multiplier: keeps the K-loop branch-free so the
    // wave-uniform basis loads can be scalarized (no divergent CF).
    const int   fc    = min(max(f, 0), LQ - 1);
    const float valid = (f >= 0 && f < LQ) ? 1.0f : 0.0f;

    float acc0[WQ], acc1[WQ];
#pragma unroll
    for (int w = 0; w < WQ; ++w) { acc0[w] = 0.0f; acc1[w] = 0.0f; }

    const float* mp  = mix  + ((size_t)b * EQ + h * EH) * LQ + fc;
    const float* kp0 = mask + (((size_t)(b * CQ)) * EQ + h * EH) * LQ + fc;
    const float* kp1 = kp0 + (size_t)EQ * LQ;      // channel 1 mask
    const float* bp  = wsT + (size_t)h * EH * WQ;  // wave-uniform

    for (int eo = 0; eo < EH; eo += 2) {
        float m0  = mp[(size_t)eo * LQ];
        float m1  = mp[(size_t)(eo + 1) * LQ];
        float k00 = kp0[(size_t)eo * LQ] * valid;
        float k01 = kp0[(size_t)(eo + 1) * LQ] * valid;
        float k10 = kp1[(size_t)eo * LQ] * valid;
        float k11 = kp1[(size_t)(eo + 1) * LQ] * valid;
        {
            float s0 = m0 * k00;
            float s1 = m0 * k10;
            const float* bb = bp + eo * WQ;        // uniform -> s_load
#pragma unroll
            for (int w = 0; w < WQ; ++w) {
                acc0[w] = fmaf(s0, bb[w], acc0[w]);
                acc1[w] = fmaf(s1, bb[w], acc1[w]);
            }
        }
        {
            float s0 = m1 * k01;
            float s1 = m1 * k11;
            const float* bb = bp + (eo + 1) * WQ;  // uniform -> s_load
#pragma unroll
            for (int w = 0; w < WQ; ++w) {
                acc0[w] = fmaf(s0, bb[w], acc0[w]);
                acc1[w] = fmaf(s1, bb[w], acc1[w]);
            }
        }
    }

    // Overlap-add into LDS copy cp = h>>1. Within a copy, 4 serialized phases
    // (h-parity x ll-parity); even-ll ranges [20*ll,20*ll+40) tile [0,1280)
    // exactly, so phase 0 is a plain store (no pre-zero needed; indices
    // [1280,1300) are written by odd-ll adds but never read back).
    const int base = ll * STEP;
    const int cp   = h >> 1;
    const int hp   = h & 1;
    if (hp == 0 && (ll & 1) == 0) {
#pragma unroll
        for (int w = 0; w < WQ; ++w) {
            outS[cp][0][base + w] = acc0[w];
            outS[cp][1][base + w] = acc1[w];
        }
    }
    __syncthreads();
    if (hp == 0 && (ll & 1) == 1) {
#pragma unroll
        for (int w = 0; w < WQ; ++w) {
            outS[cp][0][base + w] += acc0[w];
            outS[cp][1][base + w] += acc1[w];
        }
    }
    __syncthreads();
    if (hp == 1 && (ll & 1) == 0) {
#pragma unroll
        for (int w = 0; w < WQ; ++w) {
            outS[cp][0][base + w] += acc0[w];
            outS[cp][1][base + w] += acc1[w];
        }
    }
    __syncthreads();
    if (hp == 1 && (ll & 1) == 1) {
#pragma unroll
        for (int w = 0; w < WQ; ++w) {
            outS[cp][0][base + w] += acc0[w];
            outS[cp][1][base + w] += acc1[w];
        }
    }
    __syncthreads();

    // Store owned span: t = 1260*bx + i  <->  outS[*][c][20 + i], i in [0,1260)
    for (int cc = 0; cc < CQ; ++cc) {
        const size_t ob = ((size_t)b * CQ + cc) * TQ + (size_t)OWN * bx;
        for (int i = tid; i < OWN; i += 512) {
            const long t = (long)OWN * bx + i;
            if (t < (long)TQ) {
                out[ob + i] = outS[0][cc][STEP + i] + outS[1][cc][STEP + i]
                            + outS[2][cc][STEP + i] + outS[3][cc][STEP + i];
            }
        }
    }
}

extern "C" void kernel_launch(void* const* d_in, const int* in_sizes, int n_in,
                              void* d_out, int out_size, void* d_ws, size_t ws_size,
                              hipStream_t stream) {
    const float* mix   = (const float*)d_in[0];
    const float* mask  = (const float*)d_in[1];
    const float* basis = (const float*)d_in[2];
    float* out = (float*)d_out;
    float* wsT = (float*)d_ws;   // needs EQ*WQ*4 = 40960 bytes

    transpose_basis_kernel<<<dim3((EQ * WQ + 255) / 256), 256, 0, stream>>>(basis, wsT);

    dim3 grid(NBX, BQ);
    decoder_kernel<<<grid, 512, 0, stream>>>(mix, mask, wsT, out);
}

// Round 3
// 243.001 us; speedup vs baseline: 1.1203x; 1.0062x over previous
//
#include <hip/hip_runtime.h>

// Problem constants (fixed by setup_inputs)
#define BQ   4
#define CQ   2
#define EQ   256
#define LQ   16000
#define WQ   40
#define STEP 20
#define TQ   ((LQ - 1) * STEP + WQ)   // 320020
#define TLF  63                       // owned-frame pitch per block (64 computed, 1 overlap)
#define OWN  (TLF * STEP)             // 1260 owned output samples per block
#define NBX  254                      // 254 * 1260 = 320040 >= 320020
#define NH   8                        // e-octants (channels merged into each thread)
#define EH   (EQ / NH)                // 32 e's per thread
#define EC   4                        // e's per staged chunk
#define NCH  (EH / EC)                // 8 chunks
#define SROWS (3 * EC)                // 12 staged rows per chunk (mix, mask c0, mask c1)
#define NCP  4                        // LDS accumulation copies (one per octant pair)
#define SPAN (TLF * STEP + WQ + STEP) // 1320 floats per (copy, c)
// LDS pool: staging view (8 waves x 2 bufs x 12 rows x 64 f) unioned with outS
#define POOLF ((NH * 2 * SROWS * 64) > (NCP * CQ * SPAN) ? (NH * 2 * SROWS * 64) : (NCP * CQ * SPAN))

// Pre-kernel: transpose basis [W][E] -> wsT [E][W] (fp32, rows contiguous)
// so the main loop can read each e-row with wave-uniform scalar loads.
__global__ void transpose_basis_kernel(const float* __restrict__ basis,
                                       float* __restrict__ wsT) {
    int i = blockIdx.x * 256 + threadIdx.x;
    if (i < EQ * WQ) {
        int e = i / WQ;
        int w = i - e * WQ;
        wsT[i] = basis[w * EQ + e];
    }
}

// Stage one chunk (EC rows of mix + EC of mask c0 + EC of mask c1, 64 f-floats
// each) into this wave's private LDS buffer via global_load_lds: per-lane
// global addr = row + ll*4, LDS dest = uniform base + lane*4 (linear match).
// No waitcnt here — loads stay in flight under the previous chunk's FMAs.
__device__ __forceinline__ void stage_chunk(const float* mpB, const float* kpB0,
                                            const float* kpB1, float* dstBase,
                                            int e0, int ll) {
#pragma unroll
    for (int r = 0; r < EC; ++r)
        __builtin_amdgcn_global_load_lds(
            (const __attribute__((address_space(1))) void*)(mpB + (size_t)(e0 + r) * LQ + ll),
            (__attribute__((address_space(3))) void*)(dstBase + r * 64), 4, 0, 0);
#pragma unroll
    for (int r = 0; r < EC; ++r)
        __builtin_amdgcn_global_load_lds(
            (const __attribute__((address_space(1))) void*)(kpB0 + (size_t)(e0 + r) * LQ + ll),
            (__attribute__((address_space(3))) void*)(dstBase + (EC + r) * 64), 4, 0, 0);
#pragma unroll
    for (int r = 0; r < EC; ++r)
        __builtin_amdgcn_global_load_lds(
            (const __attribute__((address_space(1))) void*)(kpB1 + (size_t)(e0 + r) * LQ + ll),
            (__attribute__((address_space(3))) void*)(dstBase + (2 * EC + r) * 64), 4, 0, 0);
}

// FMA body identical to the proven round-2 pattern; m/k come from LDS
// (ds_read_b32, consecutive lanes -> 2-way bank alias = free), basis rows stay
// wave-uniform s_loads.
__device__ __forceinline__ void compute_chunk(const float* sl, int idx, float valid,
                                              const float* bbB,
                                              float acc0[WQ], float acc1[WQ]) {
#pragma unroll
    for (int eo = 0; eo < EC; eo += 2) {
        float m0  = sl[(eo)*64 + idx];
        float m1  = sl[(eo + 1)*64 + idx];
        float k00 = sl[(EC + eo)*64 + idx] * valid;
        float k01 = sl[(EC + eo + 1)*64 + idx] * valid;
        float k10 = sl[(2*EC + eo)*64 + idx] * valid;
        float k11 = sl[(2*EC + eo + 1)*64 + idx] * valid;
        {
            float s0 = m0 * k00;
            float s1 = m0 * k10;
            const float* bb = bbB + eo * WQ;       // uniform -> s_load
#pragma unroll
            for (int w = 0; w < WQ; ++w) {
                acc0[w] = fmaf(s0, bb[w], acc0[w]);
                acc1[w] = fmaf(s1, bb[w], acc1[w]);
            }
        }
        {
            float s0 = m1 * k01;
            float s1 = m1 * k11;
            const float* bb = bbB + (eo + 1) * WQ; // uniform -> s_load
#pragma unroll
            for (int w = 0; w < WQ; ++w) {
                acc0[w] = fmaf(s0, bb[w], acc0[w]);
                acc1[w] = fmaf(s1, bb[w], acc1[w]);
            }
        }
    }
}

// One block: 512 threads = 8 e-octants (h) x 64 frames (ll); both channels per
// thread. Double-buffered per-wave LDS staging with counted vmcnt(12): chunk
// t+1's 12 global_load_lds stay in flight under chunk t's 320 FMAs, breaking
// the per-iteration load-latency round trip that capped rounds 0/2 at 25% VALU.
// Overlap-add into 4 LDS copies (pool reused after a barrier), 4 serialized
// parity phases -> no atomics. Block stores t in [1260*bx, 1260*bx+1260).
__global__ __launch_bounds__(512, 3) void decoder_kernel(
    const float* __restrict__ mix,    // [B,E,L]
    const float* __restrict__ mask,   // [B,C,E,L]
    const float* __restrict__ wsT,    // [E,W] transposed basis
    float* __restrict__ out)          // [B,C,T]
{
    __shared__ float poolF[POOLF];    // 48 KB: staging during K, outS after

    const int tid = threadIdx.x;
    const int ll  = tid & 63;                                  // frame lane
    const int h   = __builtin_amdgcn_readfirstlane(tid >> 6);  // e-octant, forced uniform
    const int bx  = blockIdx.x;
    const int b   = blockIdx.y;
    const int f0  = TLF * bx - 1;        // first frame of this block's window
    const int f   = f0 + ll;             // may be out of [0,LQ)

    // Staged window start (always fully in-bounds), per-thread clamp + valid.
    const int   f0c   = min(max(f0, 0), LQ - 64);
    const int   fc    = min(max(f, 0), LQ - 1);
    const int   idx   = fc - f0c;        // in [0,63]
    const float valid = (f >= 0 && f < LQ) ? 1.0f : 0.0f;

    float acc0[WQ], acc1[WQ];
#pragma unroll
    for (int w = 0; w < WQ; ++w) { acc0[w] = 0.0f; acc1[w] = 0.0f; }

    const float* mpB  = mix  + ((size_t)b * EQ + h * EH) * LQ + f0c;
    const float* kpB0 = mask + (((size_t)(b * CQ)) * EQ + h * EH) * LQ + f0c;
    const float* kpB1 = kpB0 + (size_t)EQ * LQ;     // channel 1 mask
    const float* bp   = wsT + (size_t)h * EH * WQ;  // wave-uniform

    float* myStage0 = poolF + (h * 2 + 0) * (SROWS * 64);
    float* myStage1 = poolF + (h * 2 + 1) * (SROWS * 64);

    // ---- double-buffered pipelined K loop (counted vmcnt, never 0 mid-loop)
    stage_chunk(mpB, kpB0, kpB1, myStage0, 0, ll);
#pragma unroll 1
    for (int t = 0; t < NCH - 1; ++t) {
        float* nxt = ((t + 1) & 1) ? myStage1 : myStage0;
        stage_chunk(mpB, kpB0, kpB1, nxt, (t + 1) * EC, ll);
        asm volatile("s_waitcnt vmcnt(12)" ::: "memory");  // prev chunk landed
        __builtin_amdgcn_sched_barrier(0);
        const float* cur = (t & 1) ? myStage1 : myStage0;
        compute_chunk(cur, idx, valid, bp + t * EC * WQ, acc0, acc1);
    }
    asm volatile("s_waitcnt vmcnt(0)" ::: "memory");
    __builtin_amdgcn_sched_barrier(0);
    compute_chunk(myStage1, idx, valid, bp + (NCH - 1) * EC * WQ, acc0, acc1);

    // Staging is dead; pool is reused as outS. Sync before overwriting.
    __syncthreads();
    float (*outS)[CQ][SPAN] = (float (*)[CQ][SPAN])poolF;   // [NCP][CQ][SPAN]

    // Overlap-add into LDS copy cp = h>>1. 4 serialized parity phases
    // (h-parity x ll-parity); even-ll ranges [20*ll,20*ll+40) tile [0,1280)
    // exactly, so phase 0 is a plain store (no pre-zero needed; indices
    // [1280,1300) get garbage adds from odd-ll but are never read back).
    const int base = ll * STEP;
    const int cp   = h >> 1;
    const int hp   = h & 1;
    if (hp == 0 && (ll & 1) == 0) {
#pragma unroll
        for (int w = 0; w < WQ; ++w) {
            outS[cp][0][base + w] = acc0[w];
            outS[cp][1][base + w] = acc1[w];
        }
    }
    __syncthreads();
    if (hp == 0 && (ll & 1) == 1) {
#pragma unroll
        for (int w = 0; w < WQ; ++w) {
            outS[cp][0][base + w] += acc0[w];
            outS[cp][1][base + w] += acc1[w];
        }
    }
    __syncthreads();
    if (hp == 1 && (ll & 1) == 0) {
#pragma unroll
        for (int w = 0; w < WQ; ++w) {
            outS[cp][0][base + w] += acc0[w];
            outS[cp][1][base + w] += acc1[w];
        }
    }
    __syncthreads();
    if (hp == 1 && (ll & 1) == 1) {
#pragma unroll
        for (int w = 0; w < WQ; ++w) {
            outS[cp][0][base + w] += acc0[w];
            outS[cp][1][base + w] += acc1[w];
        }
    }
    __syncthreads();

    // Store owned span: t = 1260*bx + i  <->  outS[*][c][20 + i], i in [0,1260)
    for (int cc = 0; cc < CQ; ++cc) {
        const size_t ob = ((size_t)b * CQ + cc) * TQ + (size_t)OWN * bx;
        for (int i = tid; i < OWN; i += 512) {
            const long t = (long)OWN * bx + i;
            if (t < (long)TQ) {
                out[ob + i] = outS[0][cc][STEP + i] + outS[1][cc][STEP + i]
                            + outS[2][cc][STEP + i] + outS[3][cc][STEP + i];
            }
        }
    }
}

extern "C" void kernel_launch(void* const* d_in, const int* in_sizes, int n_in,
                              void* d_out, int out_size, void* d_ws, size_t ws_size,
                              hipStream_t stream) {
    const float* mix   = (const float*)d_in[0];
    const float* mask  = (const float*)d_in[1];
    const float* basis = (const float*)d_in[2];
    float* out = (float*)d_out;
    float* wsT = (float*)d_ws;   // needs EQ*WQ*4 = 40960 bytes

    transpose_basis_kernel<<<dim3((EQ * WQ + 255) / 256), 256, 0, stream>>>(basis, wsT);

    dim3 grid(NBX, BQ);
    decoder_kernel<<<grid, 512, 0, stream>>>(mix, mask, wsT, out);
}